// Round 9
// baseline (982.675 us; speedup 1.0000x reference)
//
#include <hip/hip_runtime.h>
#include <hip/hip_bf16.h>
#include <math.h>

// FactorizedVectorQuantizer MI355X (gfx950) — R9: W via global/L1 with rolling
// register prefetch (LDS pipe was the binding resource at 16:1 FMA:ds_read);
// X stays LDS slab-double-buffered via global_load_lds. New mix 32:1 -> FMA-bound.
//
// rows 32768, feats 256 = 128 shape + 128 color; codebooks 8192x128, 512x128.
// Bit-exact numpy pipeline: D = fmaf(-2, dot, S + t); dot and S are single
// serial ascending-k fp32 FMA chains; argmin = lowest index on ties via
// strict-< ascending scan + packed u64 atomicMin key (mono(D)<<32 | code).

#define NROWS   32768
#define NSHAPE  8192
#define NCOLOR  512
#define HALF    128
#define NCODES  8704                // 8192 + 512 transposed columns

#define NSB     16384               // 256 rowblks x 64 colblks (shape)
#define NCB     1024                // 256 rowblks x 4 colblks (color)
#define NBLKS   (NSB + NCB)         // 17408, divisible by 8

// workspace byte offsets (Wt lives in d_out scratch, not here)
#define OFF_TS    0u                // f32[8192]
#define OFF_TC    32768u            // f32[512]
#define OFF_CNT_S 34816u            // u32[8192]
#define OFF_CNT_C 67584u            // u32[512]
#define OFF_LOSS  69632u            // double
#define OFF_SS    69648u            // f32[32768]
#define OFF_SC    200720u           // f32[32768]
#define OFF_BS    331792u           // u64[32768] packed best (shape)
#define OFF_BC    593936u           // u64[32768] packed best (color)
#define OFF_END   856080u

typedef __attribute__((address_space(3))) unsigned int  lds_u32;
typedef __attribute__((address_space(1))) const unsigned int gbl_u32;

__device__ __forceinline__ unsigned mono_f32(float d) {
    unsigned u = __float_as_uint(d);
    return (u & 0x80000000u) ? ~u : (u | 0x80000000u);
}

// fused prep: codes_sq (34 blocks) | rows_sq (128 blocks) | W transpose (544)
__global__ __launch_bounds__(256) void prep_k(
    const float* __restrict__ Ws, const float* __restrict__ Wc,
    const float* __restrict__ input,
    float* __restrict__ ts, float* __restrict__ tc,
    float* __restrict__ Ss, float* __restrict__ Sc,
    float* __restrict__ Wt)
{
    __shared__ float tile[32][65];
    int blk = blockIdx.x, tid = threadIdx.x;
    if (blk < 34) {
        int j = blk * 256 + tid;            // 0..8703
        const float* w; int jl;
        if (j < NSHAPE) { w = Ws + (size_t)j * HALF; jl = j; }
        else            { w = Wc + (size_t)(j - NSHAPE) * HALF; jl = j - NSHAPE; }
        float s = 0.f;
        #pragma unroll
        for (int k = 0; k < HALF; ++k) s = fmaf(w[k], w[k], s);
        if (j < NSHAPE) ts[jl] = s; else tc[jl] = s;
    } else if (blk < 162) {
        int r = (blk - 34) * 256 + tid;
        int b = r >> 10, hw = r & 1023;
        const float* __restrict__ xin = input + ((size_t)b << 18) + hw;
        float s = 0.f;
        #pragma unroll
        for (int k = 0; k < HALF; ++k) {
            float v = xin[(size_t)k << 10];
            s = fmaf(v, v, s);
        }
        Ss[r] = s;
        float s2 = 0.f;
        #pragma unroll
        for (int k = 0; k < HALF; ++k) {
            float v = xin[(size_t)(k + HALF) << 10];
            s2 = fmaf(v, v, s2);
        }
        Sc[r] = s2;
    } else {
        int b2 = blk - 162;                 // 0..543
        int cblk = b2 % 136, kblk = b2 / 136;
        int c0 = cblk << 6, k0 = kblk << 5;
        const float* src; int cl0;
        if (c0 < NSHAPE) { src = Ws; cl0 = c0; } else { src = Wc; cl0 = c0 - NSHAPE; }
        int kk = tid & 31, cc = tid >> 5;
        #pragma unroll
        for (int p = 0; p < 8; ++p) {
            int c = cc + (p << 3);
            tile[kk][c] = src[(size_t)(cl0 + c) * HALF + k0 + kk];
        }
        __syncthreads();
        int c2 = tid & 63, kr0 = (tid >> 6) << 3;
        #pragma unroll
        for (int p = 0; p < 8; ++p) {
            int kr = kr0 + p;
            Wt[(size_t)(k0 + kr) * NCODES + c0 + c2] = tile[kr][c2];
        }
    }
}

#define FMA_ROW(i, xv) \
    acc[i][0] = fmaf(xv, w0.x, acc[i][0]); acc[i][1] = fmaf(xv, w0.y, acc[i][1]); \
    acc[i][2] = fmaf(xv, w0.z, acc[i][2]); acc[i][3] = fmaf(xv, w0.w, acc[i][3]); \
    acc[i][4] = fmaf(xv, w1.x, acc[i][4]); acc[i][5] = fmaf(xv, w1.y, acc[i][5]); \
    acc[i][6] = fmaf(xv, w1.z, acc[i][6]); acc[i][7] = fmaf(xv, w1.w, acc[i][7]);

__global__ __launch_bounds__(256, 4) void gemm_argmin_k(
    const float* __restrict__ input, const float* __restrict__ wtg,
    const float* __restrict__ ts, const float* __restrict__ tc,
    const float* __restrict__ Ss, const float* __restrict__ Sc,
    unsigned long long* __restrict__ bs, unsigned long long* __restrict__ bc)
{
    __shared__ __align__(16) char smem[17408];   // x dbuf 16KB; epilogue 17.4KB
    float (*xs2)[16][128] = reinterpret_cast<float(*)[16][128]>(smem);

    int d = blockIdx.x;
    int o = (d & 7) * (NBLKS / 8) + (d >> 3);   // bijective XCD swizzle

    int rowblk, c0w, cgb, featoff;
    const float* tv; const float* Sarr; unsigned long long* bestArr;
    if (o < NSB) {
        rowblk = o >> 6; int cb = o & 63;
        c0w = cb << 7; cgb = cb << 7; featoff = 0;
        tv = ts; Sarr = Ss; bestArr = bs;
    } else {
        int o2 = o - NSB;
        rowblk = o2 >> 2; int cb = o2 & 3;
        c0w = NSHAPE + (cb << 7); cgb = cb << 7; featoff = HALF;
        tv = tc; Sarr = Sc; bestArr = bc;
    }

    int tid = threadIdx.x;
    int lane = tid & 63;
    int wv = __builtin_amdgcn_readfirstlane(tid >> 6);   // wave id 0..3
    int r0 = rowblk << 7;
    int b = r0 >> 10, hw0 = r0 & 1023;

    // per-lane X DMA source base (one 16B chunk per lane; 1 inst = 2 k-rows)
    const float* __restrict__ xg =
        input + ((size_t)b << 18) + ((size_t)featoff << 10) + hw0
              + ((size_t)(lane >> 5) << 10) + ((lane & 31) << 2);

    int tr = tid & 15, tcg = tid >> 4;
    int tr4 = tr << 2, tc4 = tcg << 2;
    int kw = wv << 2;   // this wave's 4 k-rows within a slab

    // W column pointer for this thread (16B chunk; 16 lanes share -> 1 line/wave)
    const float* __restrict__ wp = wtg + c0w + tc4;

    float acc[8][8] = {{0.f}};

    // ---- prologue: DMA X slab 0; W rolling prefetch k=0,1 ----
    #pragma unroll
    for (int i = 0; i < 2; ++i) {
        int kx = kw + (i << 1);                          // wave-uniform
        __builtin_amdgcn_global_load_lds(
            (gbl_u32*)(xg + ((size_t)kx << 10)),
            (lds_u32*)&xs2[0][kx][0], 16, 0, 0);
    }
    float4 wa0 = *(const float4*)(wp);
    float4 wb0 = *(const float4*)(wp + 64);
    float4 wa1 = *(const float4*)(wp + NCODES);
    float4 wb1 = *(const float4*)(wp + NCODES + 64);
    __syncthreads();

    for (int s = 0; s < 8; ++s) {
        // ---- issue X DMA for slab s+1 into the other buffer ----
        if (s < 7) {
            int k0 = (s + 1) << 4;
            #pragma unroll
            for (int i = 0; i < 2; ++i) {
                int kx = kw + (i << 1);
                __builtin_amdgcn_global_load_lds(
                    (gbl_u32*)(xg + ((size_t)(k0 + kx) << 10)),
                    (lds_u32*)&xs2[(s + 1) & 1][kx][0], 16, 0, 0);
            }
        }

        // ---- compute slab s: serial ascending-k FMA chains per acc[i][j] --
        const float (*xsb)[128] = xs2[s & 1];
        #pragma unroll
        for (int kk = 0; kk < 16; ++kk) {
            int k = (s << 4) + kk;
            // prefetch W(k+2) (distance-2 rolling regs; clamp at end, unused)
            int kp = (k + 2 < 127) ? (k + 2) : 127;
            const float* wpp = wp + (size_t)kp * NCODES;
            float4 na = *(const float4*)(wpp);
            float4 nb = *(const float4*)(wpp + 64);
            const float4 x0 = *(const float4*)&xsb[kk][tr4];
            const float4 x1 = *(const float4*)&xsb[kk][64 + tr4];
            const float4 w0 = wa0;
            const float4 w1 = wb0;
            FMA_ROW(0, x0.x) FMA_ROW(1, x0.y) FMA_ROW(2, x0.z) FMA_ROW(3, x0.w)
            FMA_ROW(4, x1.x) FMA_ROW(5, x1.y) FMA_ROW(6, x1.z) FMA_ROW(7, x1.w)
            wa0 = wa1; wb0 = wb1; wa1 = na; wb1 = nb;
        }

        // X loads for s+1 were issued a full slab ago -> drain is cheap
        __syncthreads();
    }

    // ---- epilogue: per-thread float argmin (strict <, ascending cols) ----
    float Sr[8];
    #pragma unroll
    for (int i = 0; i < 8; ++i) {
        int rl = ((i & 4) << 4) + tr4 + (i & 3);
        Sr[i] = Sarr[r0 + rl];
    }
    float bestD[8]; int bestC[8];
    #pragma unroll
    for (int i = 0; i < 8; ++i) { bestD[i] = INFINITY; bestC[i] = 0; }
    #pragma unroll
    for (int j = 0; j < 8; ++j) {
        int cl = ((j & 4) << 4) + tc4 + (j & 3);
        int cgj = cgb + cl;
        float tj = tv[cgj];
        #pragma unroll
        for (int i = 0; i < 8; ++i) {
            float Sp = Sr[i] + tj;
            float D = fmaf(-2.0f, acc[i][j], Sp);   // == Sp - 2*a bitwise
            if (D < bestD[i]) { bestD[i] = D; bestC[i] = cgj; }
        }
    }

    __syncthreads();   // tiles dead; reuse smem as reduction grid [128][17] u64
    unsigned long long* red = reinterpret_cast<unsigned long long*>(smem);
    #pragma unroll
    for (int i = 0; i < 8; ++i) {
        int rl = ((i & 4) << 4) + tr4 + (i & 3);
        red[rl * 17 + tcg] =
            ((unsigned long long)mono_f32(bestD[i]) << 32) | (unsigned)bestC[i];
    }
    __syncthreads();
    if (tid < 128) {
        unsigned long long m = red[tid * 17];
        #pragma unroll
        for (int q = 1; q < 16; ++q) {
            unsigned long long v = red[tid * 17 + q];
            if (v < m) m = v;
        }
        atomicMin(&bestArr[r0 + tid], m);
    }
}

__global__ __launch_bounds__(256) void finalize_k(
    const float* __restrict__ input,
    const float* __restrict__ Ws, const float* __restrict__ Wc,
    const unsigned long long* __restrict__ bs,
    const unsigned long long* __restrict__ bc,
    unsigned* __restrict__ cnt_s, unsigned* __restrict__ cnt_c,
    double* __restrict__ loss_sum, float* __restrict__ out)
{
    int tid = threadIdx.x;
    int r = blockIdx.x * 256 + tid;

    int bi = (int)(bs[r] & 0xFFFFFFFFu);
    int ci = (int)(bc[r] & 0xFFFFFFFFu);
    atomicAdd(&cnt_s[bi], 1u);
    atomicAdd(&cnt_c[ci], 1u);

    int b = r >> 10; int hw = r & 1023;
    const float* __restrict__ xin = input + ((size_t)b << 18) + hw;
    float* __restrict__ op = out + ((size_t)b << 18) + hw;
    const float* __restrict__ qs = Ws + ((size_t)bi << 7);
    const float* __restrict__ qc = Wc + ((size_t)ci << 7);

    double ls = 0.0;
    #pragma unroll 8
    for (int c = 0; c < HALF; ++c) {
        float f = xin[(size_t)c << 10];
        float dd = qs[c] - f;                  // fp32(q - f)
        op[(size_t)c << 10] = f + dd;          // fp32(f + fp32(q - f))
        ls += (double)dd * (double)dd;
    }
    #pragma unroll 8
    for (int c = 0; c < HALF; ++c) {
        float f = xin[(size_t)(c + HALF) << 10];
        float dd = qc[c] - f;
        op[(size_t)(c + HALF) << 10] = f + dd;
        ls += (double)dd * (double)dd;
    }

    __shared__ double red[256];
    red[tid] = ls;
    __syncthreads();
    for (int s = 128; s > 0; s >>= 1) {
        if (tid < s) red[tid] += red[tid + s];
        __syncthreads();
    }
    if (tid == 0) atomicAdd(loss_sum, red[0]);
}

__global__ __launch_bounds__(256) void scalars_k(
    const unsigned* __restrict__ cnt_s, const unsigned* __restrict__ cnt_c,
    const double* __restrict__ loss_sum, float* __restrict__ out3)
{
    int tid = threadIdx.x;
    double es = 0.0, ec = 0.0;
    for (int j = tid; j < NSHAPE; j += 256) {
        float p = (float)cnt_s[j] / 32768.0f;
        es += (double)(p * logf(p + 1e-10f));
    }
    for (int j = tid; j < NCOLOR; j += 256) {
        float p = (float)cnt_c[j] / 32768.0f;
        ec += (double)(p * logf(p + 1e-10f));
    }
    __shared__ double r1[256], r2[256];
    r1[tid] = es; r2[tid] = ec;
    __syncthreads();
    for (int s = 128; s > 0; s >>= 1) {
        if (tid < s) { r1[tid] += r1[tid + s]; r2[tid] += r2[tid + s]; }
        __syncthreads();
    }
    if (tid == 0) {
        out3[0] = (float)(1.25 * loss_sum[0] / 8388608.0);  // q + 0.25*e latent
        out3[1] = expf(-(float)r1[0]);
        out3[2] = expf(-(float)r2[0]);
    }
}

extern "C" void kernel_launch(void* const* d_in, const int* in_sizes, int n_in,
                              void* d_out, int out_size, void* d_ws, size_t ws_size,
                              hipStream_t stream)
{
    const float* input = (const float*)d_in[0];
    const float* Ws    = (const float*)d_in[1];
    const float* Wc    = (const float*)d_in[2];
    float* out = (float*)d_out;
    char* ws = (char*)d_ws;

    float*    ts       = (float*)(ws + OFF_TS);
    float*    tcx      = (float*)(ws + OFF_TC);
    unsigned* cnt_s    = (unsigned*)(ws + OFF_CNT_S);
    unsigned* cnt_c    = (unsigned*)(ws + OFF_CNT_C);
    double*   loss_sum = (double*)(ws + OFF_LOSS);
    float*    Ss       = (float*)(ws + OFF_SS);
    float*    Sc       = (float*)(ws + OFF_SC);
    unsigned long long* bs = (unsigned long long*)(ws + OFF_BS);
    unsigned long long* bc = (unsigned long long*)(ws + OFF_BC);

    // Wt[128][8704] lives in d_out (finalize_k fully overwrites d_out later)
    float* Wt = out;

    // counts + loss: zero.  best arrays: 0xFF (== u64 max sentinel).
    hipMemsetAsync(ws + OFF_CNT_S, 0, (OFF_LOSS + 8u) - OFF_CNT_S, stream);
    hipMemsetAsync(ws + OFF_BS, 0xFF, OFF_END - OFF_BS, stream);

    prep_k<<<706, 256, 0, stream>>>(Ws, Wc, input, ts, tcx, Ss, Sc, Wt);

    gemm_argmin_k<<<NBLKS, 256, 0, stream>>>(
        input, Wt, ts, tcx, Ss, Sc, bs, bc);

    finalize_k<<<NROWS / 256, 256, 0, stream>>>(
        input, Ws, Wc, bs, bc, cnt_s, cnt_c, loss_sum, out);

    scalars_k<<<1, 256, 0, stream>>>(cnt_s, cnt_c, loss_sum, out + 8388608);
}

// Round 10
// 853.337 us; speedup vs baseline: 1.1516x; 1.1516x over previous
//
#include <hip/hip_runtime.h>
#include <hip/hip_bf16.h>
#include <math.h>

// FactorizedVectorQuantizer MI355X (gfx950) — R10: R8 skeleton (BK=16 dual
// global_load_lds double-buffer) with 8x16 micro-tile: 6 ds_read_b128 per
// 128 FMA (LDS/FMA ratio 1.125 vs R8's 1.5 — R8 was LDS-issue-bound).
//
// rows 32768, feats 256 = 128 shape + 128 color; codebooks 8192x128, 512x128.
// Bit-exact numpy pipeline: D = fmaf(-2, dot, S + t); dot and S are single
// serial ascending-k fp32 FMA chains; argmin = lowest index on ties via
// strict-< ascending scan + packed u64 atomicMin key (mono(D)<<32 | code).

#define NROWS   32768
#define NSHAPE  8192
#define NCOLOR  512
#define HALF    128
#define NCODES  8704                // 8192 + 512 transposed columns

#define NSB     8192                // 256 rowblks x 32 colblks (shape)
#define NCB     512                 // 256 rowblks x 2 colblks (color)
#define NBLKS   (NSB + NCB)         // 8704, divisible by 8

// workspace byte offsets (Wt lives in d_out scratch, not here)
#define OFF_TS    0u                // f32[8192]
#define OFF_TC    32768u            // f32[512]
#define OFF_CNT_S 34816u            // u32[8192]
#define OFF_CNT_C 67584u            // u32[512]
#define OFF_LOSS  69632u            // double
#define OFF_SS    69648u            // f32[32768]
#define OFF_SC    200720u           // f32[32768]
#define OFF_BS    331792u           // u64[32768] packed best (shape)
#define OFF_BC    593936u           // u64[32768] packed best (color)
#define OFF_END   856080u

typedef __attribute__((address_space(3))) unsigned int  lds_u32;
typedef __attribute__((address_space(1))) const unsigned int gbl_u32;

__device__ __forceinline__ unsigned mono_f32(float d) {
    unsigned u = __float_as_uint(d);
    return (u & 0x80000000u) ? ~u : (u | 0x80000000u);
}

// fused prep: codes_sq (34 blocks) | rows_sq (128 blocks) | W transpose (544)
__global__ __launch_bounds__(256) void prep_k(
    const float* __restrict__ Ws, const float* __restrict__ Wc,
    const float* __restrict__ input,
    float* __restrict__ ts, float* __restrict__ tc,
    float* __restrict__ Ss, float* __restrict__ Sc,
    float* __restrict__ Wt)
{
    __shared__ float tile[32][65];
    int blk = blockIdx.x, tid = threadIdx.x;
    if (blk < 34) {
        int j = blk * 256 + tid;            // 0..8703
        const float* w; int jl;
        if (j < NSHAPE) { w = Ws + (size_t)j * HALF; jl = j; }
        else            { w = Wc + (size_t)(j - NSHAPE) * HALF; jl = j - NSHAPE; }
        float s = 0.f;
        #pragma unroll
        for (int k = 0; k < HALF; ++k) s = fmaf(w[k], w[k], s);
        if (j < NSHAPE) ts[jl] = s; else tc[jl] = s;
    } else if (blk < 162) {
        int r = (blk - 34) * 256 + tid;
        int b = r >> 10, hw = r & 1023;
        const float* __restrict__ xin = input + ((size_t)b << 18) + hw;
        float s = 0.f;
        #pragma unroll
        for (int k = 0; k < HALF; ++k) {
            float v = xin[(size_t)k << 10];
            s = fmaf(v, v, s);
        }
        Ss[r] = s;
        float s2 = 0.f;
        #pragma unroll
        for (int k = 0; k < HALF; ++k) {
            float v = xin[(size_t)(k + HALF) << 10];
            s2 = fmaf(v, v, s2);
        }
        Sc[r] = s2;
    } else {
        int b2 = blk - 162;                 // 0..543
        int cblk = b2 % 136, kblk = b2 / 136;
        int c0 = cblk << 6, k0 = kblk << 5;
        const float* src; int cl0;
        if (c0 < NSHAPE) { src = Ws; cl0 = c0; } else { src = Wc; cl0 = c0 - NSHAPE; }
        int kk = tid & 31, cc = tid >> 5;
        #pragma unroll
        for (int p = 0; p < 8; ++p) {
            int c = cc + (p << 3);
            tile[kk][c] = src[(size_t)(cl0 + c) * HALF + k0 + kk];
        }
        __syncthreads();
        int c2 = tid & 63, kr0 = (tid >> 6) << 3;
        #pragma unroll
        for (int p = 0; p < 8; ++p) {
            int kr = kr0 + p;
            Wt[(size_t)(k0 + kr) * NCODES + c0 + c2] = tile[kr][c2];
        }
    }
}

#define FMA_ROW(i, xv) \
    acc[i][ 0] = fmaf(xv, w0.x, acc[i][ 0]); acc[i][ 1] = fmaf(xv, w0.y, acc[i][ 1]); \
    acc[i][ 2] = fmaf(xv, w0.z, acc[i][ 2]); acc[i][ 3] = fmaf(xv, w0.w, acc[i][ 3]); \
    acc[i][ 4] = fmaf(xv, w1.x, acc[i][ 4]); acc[i][ 5] = fmaf(xv, w1.y, acc[i][ 5]); \
    acc[i][ 6] = fmaf(xv, w1.z, acc[i][ 6]); acc[i][ 7] = fmaf(xv, w1.w, acc[i][ 7]); \
    acc[i][ 8] = fmaf(xv, w2.x, acc[i][ 8]); acc[i][ 9] = fmaf(xv, w2.y, acc[i][ 9]); \
    acc[i][10] = fmaf(xv, w2.z, acc[i][10]); acc[i][11] = fmaf(xv, w2.w, acc[i][11]); \
    acc[i][12] = fmaf(xv, w3.x, acc[i][12]); acc[i][13] = fmaf(xv, w3.y, acc[i][13]); \
    acc[i][14] = fmaf(xv, w3.z, acc[i][14]); acc[i][15] = fmaf(xv, w3.w, acc[i][15]);

__global__ __launch_bounds__(256, 2) void gemm_argmin_k(
    const float* __restrict__ input, const float* __restrict__ wtg,
    const float* __restrict__ ts, const float* __restrict__ tc,
    const float* __restrict__ Ss, const float* __restrict__ Sc,
    unsigned long long* __restrict__ bs, unsigned long long* __restrict__ bc)
{
    __shared__ __align__(16) char smem[49152];
    float (*xs2)[16][128] = reinterpret_cast<float(*)[16][128]>(smem);          // 2x8KB
    float (*ws2)[16][256] = reinterpret_cast<float(*)[16][256]>(smem + 16384);  // 2x16KB

    int d = blockIdx.x;
    int o = (d & 7) * (NBLKS / 8) + (d >> 3);   // bijective XCD swizzle

    int rowblk, c0w, cgb, featoff;
    const float* tv; const float* Sarr; unsigned long long* bestArr;
    if (o < NSB) {
        rowblk = o >> 5; int cb = o & 31;
        c0w = cb << 8; cgb = cb << 8; featoff = 0;
        tv = ts; Sarr = Ss; bestArr = bs;
    } else {
        int o2 = o - NSB;
        rowblk = o2 >> 1; int cb = o2 & 1;
        c0w = NSHAPE + (cb << 8); cgb = cb << 8; featoff = HALF;
        tv = tc; Sarr = Sc; bestArr = bc;
    }

    int tid = threadIdx.x;
    int lane = tid & 63;
    int wv = __builtin_amdgcn_readfirstlane(tid >> 6);   // wave id 0..3
    int r0 = rowblk << 7;
    int b = r0 >> 10, hw0 = r0 & 1023;

    // X DMA source base: lane covers one 16B chunk; 1 inst = 2 k-rows (1KB)
    const float* __restrict__ xg =
        input + ((size_t)b << 18) + ((size_t)featoff << 10) + hw0
              + ((size_t)(lane >> 5) << 10) + ((lane & 31) << 2);
    // W DMA source base: 1 inst = 1 k-row of 256 floats (1KB); lane*16B
    const float* __restrict__ wg = wtg + c0w + (lane << 2);

    int tr = tid & 15, tcg = tid >> 4;
    int tr4 = tr << 2, tc4 = tcg << 2;
    int kw = wv << 2;   // this wave's 4 k-rows within a slab

    float acc[8][16];
    #pragma unroll
    for (int i = 0; i < 8; ++i)
        #pragma unroll
        for (int j = 0; j < 16; ++j) acc[i][j] = 0.f;

    // ---- prologue: DMA slab 0 (X: 2 insts/wave, W: 4 insts/wave) ----
    #pragma unroll
    for (int i = 0; i < 2; ++i) {
        int kx = kw + (i << 1);                          // wave-uniform
        __builtin_amdgcn_global_load_lds(
            (gbl_u32*)(xg + ((size_t)kx << 10)),
            (lds_u32*)&xs2[0][kx][0], 16, 0, 0);
    }
    #pragma unroll
    for (int i = 0; i < 4; ++i) {
        int kx = kw + i;
        __builtin_amdgcn_global_load_lds(
            (gbl_u32*)(wg + (size_t)kx * NCODES),
            (lds_u32*)&ws2[0][kx][0], 16, 0, 0);
    }
    __syncthreads();

    for (int s = 0; s < 8; ++s) {
        // ---- issue DMA for slab s+1 into the other buffer (issue-early) ----
        if (s < 7) {
            int k0 = (s + 1) << 4;
            #pragma unroll
            for (int i = 0; i < 2; ++i) {
                int kx = kw + (i << 1);
                __builtin_amdgcn_global_load_lds(
                    (gbl_u32*)(xg + ((size_t)(k0 + kx) << 10)),
                    (lds_u32*)&xs2[(s + 1) & 1][kx][0], 16, 0, 0);
            }
            #pragma unroll
            for (int i = 0; i < 4; ++i) {
                int kx = kw + i;
                __builtin_amdgcn_global_load_lds(
                    (gbl_u32*)(wg + (size_t)(k0 + kx) * NCODES),
                    (lds_u32*)&ws2[(s + 1) & 1][kx][0], 16, 0, 0);
            }
        }

        // ---- compute slab s: serial ascending-k FMA chains per acc[i][j] --
        const float (*xsb)[128] = xs2[s & 1];
        const float (*wsb)[256] = ws2[s & 1];
        #pragma unroll 8
        for (int kk = 0; kk < 16; ++kk) {
            const float4 x0 = *(const float4*)&xsb[kk][tr4];
            const float4 x1 = *(const float4*)&xsb[kk][64 + tr4];
            const float4 w0 = *(const float4*)&wsb[kk][tc4];
            const float4 w1 = *(const float4*)&wsb[kk][64 + tc4];
            const float4 w2 = *(const float4*)&wsb[kk][128 + tc4];
            const float4 w3 = *(const float4*)&wsb[kk][192 + tc4];
            FMA_ROW(0, x0.x) FMA_ROW(1, x0.y) FMA_ROW(2, x0.z) FMA_ROW(3, x0.w)
            FMA_ROW(4, x1.x) FMA_ROW(5, x1.y) FMA_ROW(6, x1.z) FMA_ROW(7, x1.w)
        }

        // loads for s+1 were issued a full slab ago -> drain is cheap
        __syncthreads();
    }

    // ---- epilogue: per-thread float argmin (strict <, ascending cols) ----
    float Sr[8];
    #pragma unroll
    for (int i = 0; i < 8; ++i) {
        int rl = ((i & 4) << 4) + tr4 + (i & 3);
        Sr[i] = Sarr[r0 + rl];
    }
    float bestD[8]; int bestC[8];
    #pragma unroll
    for (int i = 0; i < 8; ++i) { bestD[i] = INFINITY; bestC[i] = 0; }
    #pragma unroll
    for (int j = 0; j < 16; ++j) {
        int cl = ((j >> 2) << 6) + tc4 + (j & 3);   // quads at 0,64,128,192
        int cgj = cgb + cl;
        float tj = tv[cgj];
        #pragma unroll
        for (int i = 0; i < 8; ++i) {
            float Sp = Sr[i] + tj;
            float D = fmaf(-2.0f, acc[i][j], Sp);   // == Sp - 2*a bitwise
            if (D < bestD[i]) { bestD[i] = D; bestC[i] = cgj; }
        }
    }

    __syncthreads();   // tiles dead; reuse smem as reduction grid [128][17] u64
    unsigned long long* red = reinterpret_cast<unsigned long long*>(smem);
    #pragma unroll
    for (int i = 0; i < 8; ++i) {
        int rl = ((i & 4) << 4) + tr4 + (i & 3);
        red[rl * 17 + tcg] =
            ((unsigned long long)mono_f32(bestD[i]) << 32) | (unsigned)bestC[i];
    }
    __syncthreads();
    if (tid < 128) {
        unsigned long long m = red[tid * 17];
        #pragma unroll
        for (int q = 1; q < 16; ++q) {
            unsigned long long v = red[tid * 17 + q];
            if (v < m) m = v;
        }
        atomicMin(&bestArr[r0 + tid], m);
    }
}

__global__ __launch_bounds__(256) void finalize_k(
    const float* __restrict__ input,
    const float* __restrict__ Ws, const float* __restrict__ Wc,
    const unsigned long long* __restrict__ bs,
    const unsigned long long* __restrict__ bc,
    unsigned* __restrict__ cnt_s, unsigned* __restrict__ cnt_c,
    double* __restrict__ loss_sum, float* __restrict__ out)
{
    int tid = threadIdx.x;
    int r = blockIdx.x * 256 + tid;

    int bi = (int)(bs[r] & 0xFFFFFFFFu);
    int ci = (int)(bc[r] & 0xFFFFFFFFu);
    atomicAdd(&cnt_s[bi], 1u);
    atomicAdd(&cnt_c[ci], 1u);

    int b = r >> 10; int hw = r & 1023;
    const float* __restrict__ xin = input + ((size_t)b << 18) + hw;
    float* __restrict__ op = out + ((size_t)b << 18) + hw;
    const float* __restrict__ qs = Ws + ((size_t)bi << 7);
    const float* __restrict__ qc = Wc + ((size_t)ci << 7);

    double ls = 0.0;
    #pragma unroll 8
    for (int c = 0; c < HALF; ++c) {
        float f = xin[(size_t)c << 10];
        float dd = qs[c] - f;                  // fp32(q - f)
        op[(size_t)c << 10] = f + dd;          // fp32(f + fp32(q - f))
        ls += (double)dd * (double)dd;
    }
    #pragma unroll 8
    for (int c = 0; c < HALF; ++c) {
        float f = xin[(size_t)(c + HALF) << 10];
        float dd = qc[c] - f;
        op[(size_t)(c + HALF) << 10] = f + dd;
        ls += (double)dd * (double)dd;
    }

    __shared__ double red[256];
    red[tid] = ls;
    __syncthreads();
    for (int s = 128; s > 0; s >>= 1) {
        if (tid < s) red[tid] += red[tid + s];
        __syncthreads();
    }
    if (tid == 0) atomicAdd(loss_sum, red[0]);
}

__global__ __launch_bounds__(256) void scalars_k(
    const unsigned* __restrict__ cnt_s, const unsigned* __restrict__ cnt_c,
    const double* __restrict__ loss_sum, float* __restrict__ out3)
{
    int tid = threadIdx.x;
    double es = 0.0, ec = 0.0;
    for (int j = tid; j < NSHAPE; j += 256) {
        float p = (float)cnt_s[j] / 32768.0f;
        es += (double)(p * logf(p + 1e-10f));
    }
    for (int j = tid; j < NCOLOR; j += 256) {
        float p = (float)cnt_c[j] / 32768.0f;
        ec += (double)(p * logf(p + 1e-10f));
    }
    __shared__ double r1[256], r2[256];
    r1[tid] = es; r2[tid] = ec;
    __syncthreads();
    for (int s = 128; s > 0; s >>= 1) {
        if (tid < s) { r1[tid] += r1[tid + s]; r2[tid] += r2[tid + s]; }
        __syncthreads();
    }
    if (tid == 0) {
        out3[0] = (float)(1.25 * loss_sum[0] / 8388608.0);  // q + 0.25*e latent
        out3[1] = expf(-(float)r1[0]);
        out3[2] = expf(-(float)r2[0]);
    }
}

extern "C" void kernel_launch(void* const* d_in, const int* in_sizes, int n_in,
                              void* d_out, int out_size, void* d_ws, size_t ws_size,
                              hipStream_t stream)
{
    const float* input = (const float*)d_in[0];
    const float* Ws    = (const float*)d_in[1];
    const float* Wc    = (const float*)d_in[2];
    float* out = (float*)d_out;
    char* ws = (char*)d_ws;

    float*    ts       = (float*)(ws + OFF_TS);
    float*    tcx      = (float*)(ws + OFF_TC);
    unsigned* cnt_s    = (unsigned*)(ws + OFF_CNT_S);
    unsigned* cnt_c    = (unsigned*)(ws + OFF_CNT_C);
    double*   loss_sum = (double*)(ws + OFF_LOSS);
    float*    Ss       = (float*)(ws + OFF_SS);
    float*    Sc       = (float*)(ws + OFF_SC);
    unsigned long long* bs = (unsigned long long*)(ws + OFF_BS);
    unsigned long long* bc = (unsigned long long*)(ws + OFF_BC);

    // Wt[128][8704] lives in d_out (finalize_k fully overwrites d_out later)
    float* Wt = out;

    // counts + loss: zero.  best arrays: 0xFF (== u64 max sentinel).
    hipMemsetAsync(ws + OFF_CNT_S, 0, (OFF_LOSS + 8u) - OFF_CNT_S, stream);
    hipMemsetAsync(ws + OFF_BS, 0xFF, OFF_END - OFF_BS, stream);

    prep_k<<<706, 256, 0, stream>>>(Ws, Wc, input, ts, tcx, Ss, Sc, Wt);

    gemm_argmin_k<<<NBLKS, 256, 0, stream>>>(
        input, Wt, ts, tcx, Ss, Sc, bs, bc);

    finalize_k<<<NROWS / 256, 256, 0, stream>>>(
        input, Ws, Wc, bs, bc, cnt_s, cnt_c, loss_sum, out);

    scalars_k<<<1, 256, 0, stream>>>(cnt_s, cnt_c, loss_sum, out + 8388608);
}